// Round 18
// baseline (83.631 us; speedup 1.0000x reference)
//
#include <hip/hip_runtime.h>

#define NPTS 16384
#define GS   32
#define NC   (GS * GS * GS)
#define BBOX 4.0f
#define H    0.25f
#define INVH 4.0f
#define RMAX 15
#define TABN 29791                // 31^3 packed shell offsets, ring-sorted
#define QL   64                   // one full wave per query
#define QPB  4                    // queries (waves) per 256-thread block

__device__ __forceinline__ int cellco(float v) {
    int c = (int)floorf((v + BBOX) * INVH);
    return min(max(c, 0), GS - 1);
}

// ---- pass 1: per-cell histograms + shell-table gen (closed-form, no atomics)
__global__ void hist_k(const float* __restrict__ s, const float* __restrict__ t,
                       int* __restrict__ cntS, int* __restrict__ cntT,
                       int* __restrict__ tab) {
    int i = blockIdx.x * blockDim.x + threadIdx.x;
    if (i < 2 * NPTS) {
        int cloud = i >> 14, p = i & (NPTS - 1);
        const float* base = cloud ? t : s;
        float x = base[3 * p], y = base[3 * p + 1], z = base[3 * p + 2];
        int id = (cellco(x) * GS + cellco(y)) * GS + cellco(z);
        atomicAdd((cloud ? cntT : cntS) + id, 1);
    } else if (i - 2 * NPTS < TABN) {
        // shell table: offsets in [-15,15]^3 grouped by Chebyshev ring r;
        // ring r occupies tab[(2r-1)^3 .. (2r+1)^3). Rank within the ring is
        // CLOSED-FORM by face (no atomics): a=+r, a=-r, b=+r, b=-r, c=+r, c=-r.
        unsigned idx = i - 2 * NPTS;
        unsigned q1 = idx / 961u, rem = idx - q1 * 961u;
        unsigned q2 = rem / 31u,  q3 = rem - q2 * 31u;
        int a = (int)q1 - 15, b = (int)q2 - 15, c = (int)q3 - 15;
        int r = max(max(abs(a), abs(b)), abs(c));
        int pos = 0;
        if (r > 0) {
            int w = 2 * r - 1, W = 2 * r + 1;
            int fo;
            if (a == r)        fo = (b + r) * W + (c + r);
            else if (a == -r)  fo = W * W + (b + r) * W + (c + r);
            else if (b == r)   fo = 2 * W * W + (a + r - 1) * W + (c + r);
            else if (b == -r)  fo = 2 * W * W + w * W + (a + r - 1) * W + (c + r);
            else if (c == r)   fo = 2 * W * W + 2 * w * W + (a + r - 1) * w + (b + r - 1);
            else               fo = 2 * W * W + 2 * w * W + w * w
                                    + (a + r - 1) * w + (b + r - 1);
            pos = w * w * w + fo;
        }
        tab[pos] = ((int)q1 << 10) | ((int)q2 << 5) | (int)q3;
    }
}

// ---- pass 2: pure scan -> rng{start,start} pairs ------------------------
__global__ __launch_bounds__(1024)
void scan_k(const int* __restrict__ cntS, const int* __restrict__ cntT,
            int2* __restrict__ rngS, int2* __restrict__ rngT) {
    __shared__ int2 part[1024];
    int t = threadIdx.x;
    const int4* cS4 = (const int4*)cntS;
    const int4* cT4 = (const int4*)cntT;
    int4 bufS[8], bufT[8];
    int a = 0, b = 0;
#pragma unroll
    for (int k = 0; k < 8; ++k) {
        bufS[k] = cS4[t * 8 + k];
        bufT[k] = cT4[t * 8 + k];
        a += bufS[k].x + bufS[k].y + bufS[k].z + bufS[k].w;
        b += bufT[k].x + bufT[k].y + bufT[k].z + bufT[k].w;
    }
    part[t] = make_int2(a, b);
    __syncthreads();
    for (int off = 1; off < 1024; off <<= 1) {       // Hillis-Steele inclusive
        int2 add = (t >= off) ? part[t - off] : make_int2(0, 0);
        __syncthreads();
        part[t].x += add.x; part[t].y += add.y;
        __syncthreads();
    }
    int2 run = (t > 0) ? part[t - 1] : make_int2(0, 0);
    int4* rS4 = (int4*)rngS;
    int4* rT4 = (int4*)rngT;
#pragma unroll
    for (int k = 0; k < 8; ++k) {
        int s0 = run.x, s1 = s0 + bufS[k].x, s2 = s1 + bufS[k].y, s3 = s2 + bufS[k].z;
        run.x = s3 + bufS[k].w;
        rS4[t * 16 + 2 * k]     = make_int4(s0, s0, s1, s1);
        rS4[t * 16 + 2 * k + 1] = make_int4(s2, s2, s3, s3);
        s0 = run.y; s1 = s0 + bufT[k].x; s2 = s1 + bufT[k].y; s3 = s2 + bufT[k].z;
        run.y = s3 + bufT[k].w;
        rT4[t * 16 + 2 * k]     = make_int4(s0, s0, s1, s1);
        rT4[t * 16 + 2 * k + 1] = make_int4(s2, s2, s3, s3);
    }
}

// ---- pass 3: destructive scatter (rng.y: start -> end) ------------------
__global__ void scatter_k(const float* __restrict__ s, const float* __restrict__ t,
                          int* __restrict__ rngS, int* __restrict__ rngT,
                          float4* __restrict__ sortedS, float4* __restrict__ sortedT) {
    int i = blockIdx.x * blockDim.x + threadIdx.x;
    int cloud = i >> 14, p = i & (NPTS - 1);
    const float* base = cloud ? t : s;
    float x = base[3 * p], y = base[3 * p + 1], z = base[3 * p + 2];
    int id = (cellco(x) * GS + cellco(y)) * GS + cellco(z);
    int pos = atomicAdd((cloud ? rngT : rngS) + 2 * id + 1, 1);
    (cloud ? sortedT : sortedS)[pos] = make_float4(x, y, z, __int_as_float(p));
}

// ---- pass 4: exact NN; 4 waves = 4 queries per 256-thr block ------------
// 64-thr blocks cap at 16 workgroups/CU = 16 waves; 256-thr blocks reach the
// 32-wave/CU HW ceiling -> 2x TLP for this latency-bound kernel.
__global__ __launch_bounds__(256)
void query_k(const float4* __restrict__ sortedS, const float4* __restrict__ sortedT,
             const int2* __restrict__ rngS, const int2* __restrict__ rngT,
             const int* __restrict__ tab, float* __restrict__ out) {
    int q = blockIdx.x * QPB + (threadIdx.x >> 6);   // one wave per query
    int g = threadIdx.x & 63;
    int cloud = q >> 14, j = q & (NPTS - 1);
    float4 qp = (cloud ? sortedT : sortedS)[j];      // sorted: coherent blocks
    const float4* __restrict__ pts = cloud ? sortedS : sortedT;
    const int2* __restrict__ rng = cloud ? rngS : rngT;

    float qx = qp.x, qy = qp.y, qz = qp.z;
    int cx = cellco(qx), cy = cellco(qy), cz = cellco(qz);
    float minwall = fminf(fminf(fminf(qx - (-BBOX + cx * H), (-BBOX + (cx + 1) * H) - qx),
                                fminf(qy - (-BBOX + cy * H), (-BBOX + (cy + 1) * H) - qy)),
                          fminf(qz - (-BBOX + cz * H), (-BBOX + (cz + 1) * H) - qz));
    minwall = fmaxf(minwall, 0.0f);

    float best = 1e30f;

#define DECODE(pk, validIn, cellc, lbv)                                        \
    int cellc; float lbv;                                                      \
    {                                                                          \
        int ix = cx + ((pk) >> 10) - 15;                                       \
        int iy = cy + (((pk) >> 5) & 31) - 15;                                 \
        int iz = cz + ((pk) & 31) - 15;                                        \
        bool in = (validIn) && (unsigned)ix < GS && (unsigned)iy < GS &&       \
                  (unsigned)iz < GS;                                           \
        float clx = -BBOX + ix * H, cly = -BBOX + iy * H, clz = -BBOX + iz * H;\
        float dx = fmaxf(0.f, fmaxf(ix == 0 ? -1.f : clx - qx,                 \
                                    ix == GS - 1 ? -1.f : qx - clx - H));      \
        float dy = fmaxf(0.f, fmaxf(iy == 0 ? -1.f : cly - qy,                 \
                                    iy == GS - 1 ? -1.f : qy - cly - H));      \
        float dz = fmaxf(0.f, fmaxf(iz == 0 ? -1.f : clz - qz,                 \
                                    iz == GS - 1 ? -1.f : qz - clz - H));      \
        lbv = in ? fmaf(dx, dx, fmaf(dy, dy, dz * dz)) : 1e30f;                \
        cellc = in ? ((ix * GS + iy) * GS + iz) : 0;                           \
    }

    // 2-deep unrolled point scan: two independent loads in flight -> halves
    // the per-point waitcnt serialization.
#define PTS_SCAN(v)                                                            \
    {                                                                          \
        int k = (v).x;                                                         \
        for (; k + 2 <= (v).y; k += 2) {                                       \
            float4 p0 = pts[k], p1 = pts[k + 1];                               \
            float a0 = qx - p0.x, b0 = qy - p0.y, c0 = qz - p0.z;              \
            float a1 = qx - p1.x, b1 = qy - p1.y, c1 = qz - p1.z;              \
            best = fminf(best, fmaf(a0, a0, fmaf(b0, b0, c0 * c0)));           \
            best = fminf(best, fmaf(a1, a1, fmaf(b1, b1, c1 * c1)));           \
        }                                                                      \
        if (k < (v).y) {                                                       \
            float4 p0 = pts[k];                                                \
            float a0 = qx - p0.x, b0 = qy - p0.y, c0 = qz - p0.z;              \
            best = fminf(best, fmaf(a0, a0, fmaf(b0, b0, c0 * c0)));           \
        }                                                                      \
    }

    {   // ring 0: home cell, strided over the wave
        int c = (cx * GS + cy) * GS + cz;
        int2 v = rng[c];
        for (int k = v.x + g; k < v.y; k += QL) {
            float4 p = pts[k];
            float ax = qx - p.x, ay = qy - p.y, az = qz - p.z;
            best = fminf(best, fmaf(ax, ax, fmaf(ay, ay, az * az)));
        }
    }

    for (int r = 1; r < GS; ++r) {
        float bu = best;                              // wave-uniform best
        bu = fminf(bu, __shfl_xor(bu, 1, 64));
        bu = fminf(bu, __shfl_xor(bu, 2, 64));
        bu = fminf(bu, __shfl_xor(bu, 4, 64));
        bu = fminf(bu, __shfl_xor(bu, 8, 64));
        bu = fminf(bu, __shfl_xor(bu, 16, 64));
        bu = fminf(bu, __shfl_xor(bu, 32, 64));
        float lbr = minwall + (float)(r - 1) * H;
        best = bu;
        if (lbr * lbr >= bu) break;                   // wave-uniform exit

        if (r <= RMAX) {                              // table-driven, 2-slot batch
            int w = 2 * r - 1, W = 2 * r + 1;
            int i0 = w * w * w, i1 = W * W * W;
            for (int base = i0 + g; base < i1; base += 2 * QL) {
                int iB = base + QL;
                int pkA = tab[base];                  // unconditional loads
                int pkB = tab[iB < i1 ? iB : base];
                DECODE(pkA, true, cA, lbA)
                DECODE(pkB, iB < i1, cB, lbB)
                int2 vA = rng[cA];                    // both in flight together
                int2 vB = rng[cB];
                if (lbA < best) PTS_SCAN(vA)
                if (lbB < best) PTS_SCAN(vB)
            }
        } else {                                      // r>15: NN dist > 3.5 — ~never
            unsigned W = 2 * r + 1, W2 = W * W, tot = W2 * W;
            for (unsigned idx = g; idx < tot; idx += QL) {
                unsigned q1 = idx / W2, rem = idx - q1 * W2;
                unsigned q2 = rem / W, q3 = rem - q2 * W;
                int dxo = (int)q1 - r, dyo = (int)q2 - r, dzo = (int)q3 - r;
                if (max(max(abs(dxo), abs(dyo)), abs(dzo)) != r) continue;
                int ix = cx + dxo, iy = cy + dyo, iz = cz + dzo;
                if ((unsigned)ix >= GS || (unsigned)iy >= GS || (unsigned)iz >= GS)
                    continue;
                int pk = ((ix - cx + 15) << 10) | ((iy - cy + 15) << 5) | (iz - cz + 15);
                DECODE(pk, true, cc, lbc)
                if (lbc < best) { int2 v = rng[cc]; PTS_SCAN(v) }
            }
        }
    }
#undef PTS_SCAN
#undef DECODE

    float bu = best;
    bu = fminf(bu, __shfl_xor(bu, 1, 64));
    bu = fminf(bu, __shfl_xor(bu, 2, 64));
    bu = fminf(bu, __shfl_xor(bu, 4, 64));
    bu = fminf(bu, __shfl_xor(bu, 8, 64));
    bu = fminf(bu, __shfl_xor(bu, 16, 64));
    bu = fminf(bu, __shfl_xor(bu, 32, 64));
    if (g == 0) out[cloud * NPTS + __float_as_int(qp.w)] = bu;
}

extern "C" void kernel_launch(void* const* d_in, const int* in_sizes, int n_in,
                              void* d_out, int out_size, void* d_ws, size_t ws_size,
                              hipStream_t stream) {
    const float* s = (const float*)d_in[0];
    const float* t = (const float*)d_in[1];

    int* wsI = (int*)d_ws;
    int* cntS  = wsI;                        // NC
    int* cntT  = wsI + NC;                   // NC
    int2* rngS = (int2*)(wsI + 2 * NC);      // NC int2
    int2* rngT = rngS + NC;                  // NC int2
    int* tab   = wsI + 6 * NC;               // 29792 (padded)
    float4* sortedS = (float4*)(wsI + 6 * NC + 29792);   // NPTS
    float4* sortedT = sortedS + NPTS;                    // NPTS

    hipMemsetAsync(cntS, 0, (size_t)2 * NC * sizeof(int), stream);
    hist_k<<<(2 * NPTS + TABN + 255) / 256, 256, 0, stream>>>(s, t, cntS, cntT, tab);
    scan_k<<<1, 1024, 0, stream>>>(cntS, cntT, rngS, rngT);
    scatter_k<<<(2 * NPTS) / 256, 256, 0, stream>>>(s, t, (int*)rngS, (int*)rngT,
                                                    sortedS, sortedT);
    query_k<<<(2 * NPTS) / QPB, 256, 0, stream>>>(sortedS, sortedT, rngS, rngT, tab,
                                                  (float*)d_out);
}

// Round 19
// 59.271 us; speedup vs baseline: 1.4110x; 1.4110x over previous
//
#include <hip/hip_runtime.h>

#define NPTS 16384
#define GS   32
#define NC   (GS * GS * GS)
#define BBOX 4.0f
#define H    0.25f
#define INVH 4.0f
#define RMAX 15
#define TABN 29791                // 31^3 packed shell offsets, ring-sorted
#define QL   64                   // one full wave per query
#define QPB  4                    // queries (waves) per 256-thread block

__device__ __forceinline__ int cellco(float v) {
    int c = (int)floorf((v + BBOX) * INVH);
    return min(max(c, 0), GS - 1);
}

// ---- pass 1: per-cell histograms + shell-table gen (closed-form, no atomics)
__global__ void hist_k(const float* __restrict__ s, const float* __restrict__ t,
                       int* __restrict__ cntS, int* __restrict__ cntT,
                       int* __restrict__ tab) {
    int i = blockIdx.x * blockDim.x + threadIdx.x;
    if (i < 2 * NPTS) {
        int cloud = i >> 14, p = i & (NPTS - 1);
        const float* base = cloud ? t : s;
        float x = base[3 * p], y = base[3 * p + 1], z = base[3 * p + 2];
        int id = (cellco(x) * GS + cellco(y)) * GS + cellco(z);
        atomicAdd((cloud ? cntT : cntS) + id, 1);
    } else if (i - 2 * NPTS < TABN) {
        // ring r occupies tab[(2r-1)^3 .. (2r+1)^3); rank is CLOSED-FORM by face.
        unsigned idx = i - 2 * NPTS;
        unsigned q1 = idx / 961u, rem = idx - q1 * 961u;
        unsigned q2 = rem / 31u,  q3 = rem - q2 * 31u;
        int a = (int)q1 - 15, b = (int)q2 - 15, c = (int)q3 - 15;
        int r = max(max(abs(a), abs(b)), abs(c));
        int pos = 0;
        if (r > 0) {
            int w = 2 * r - 1, W = 2 * r + 1;
            int fo;
            if (a == r)        fo = (b + r) * W + (c + r);
            else if (a == -r)  fo = W * W + (b + r) * W + (c + r);
            else if (b == r)   fo = 2 * W * W + (a + r - 1) * W + (c + r);
            else if (b == -r)  fo = 2 * W * W + w * W + (a + r - 1) * W + (c + r);
            else if (c == r)   fo = 2 * W * W + 2 * w * W + (a + r - 1) * w + (b + r - 1);
            else               fo = 2 * W * W + 2 * w * W + w * w
                                    + (a + r - 1) * w + (b + r - 1);
            pos = w * w * w + fo;
        }
        tab[pos] = ((int)q1 << 10) | ((int)q2 << 5) | (int)q3;
    }
}

// ---- pass 2a: per-block (256-cell chunk) count totals --------------------
__global__ __launch_bounds__(256)
void sums_k(const int* __restrict__ cntS, const int* __restrict__ cntT,
            int2* __restrict__ bsum) {
    __shared__ int2 wsum[4];
    int c = blockIdx.x * 256 + threadIdx.x;
    int a = cntS[c], b = cntT[c];
#pragma unroll
    for (int o = 1; o < 64; o <<= 1) {
        a += __shfl_xor(a, o, 64);
        b += __shfl_xor(b, o, 64);
    }
    if ((threadIdx.x & 63) == 0) wsum[threadIdx.x >> 6] = make_int2(a, b);
    __syncthreads();
    if (threadIdx.x == 0) {
        int2 r = wsum[0];
        r.x += wsum[1].x + wsum[2].x + wsum[3].x;
        r.y += wsum[1].y + wsum[2].y + wsum[3].y;
        bsum[blockIdx.x] = r;
    }
}

// ---- pass 2b: 128 parallel blocks: scan block totals (redundant, 512B) +
// local 256-cell scan -> rng{start,start} ----------------------------------
__global__ __launch_bounds__(256)
void scan2_k(const int* __restrict__ cntS, const int* __restrict__ cntT,
             const int2* __restrict__ bsum,
             int2* __restrict__ rngS, int2* __restrict__ rngT) {
    __shared__ int2 loc[256];
    __shared__ int2 boff[128];
    int t = threadIdx.x;
    if (t < 128) boff[t] = bsum[t];
    int c = blockIdx.x * 256 + t;
    int2 mine = make_int2(cntS[c], cntT[c]);
    loc[t] = mine;
    __syncthreads();
    for (int o = 1; o < 128; o <<= 1) {              // scan block totals
        int2 add = (t < 128 && t >= o) ? boff[t - o] : make_int2(0, 0);
        __syncthreads();
        if (t < 128) { boff[t].x += add.x; boff[t].y += add.y; }
        __syncthreads();
    }
    for (int o = 1; o < 256; o <<= 1) {              // local inclusive scan
        int2 add = (t >= o) ? loc[t - o] : make_int2(0, 0);
        __syncthreads();
        loc[t].x += add.x; loc[t].y += add.y;
        __syncthreads();
    }
    int2 bo = (blockIdx.x > 0) ? boff[blockIdx.x - 1] : make_int2(0, 0);
    int sx = bo.x + loc[t].x - mine.x;               // exclusive
    int sy = bo.y + loc[t].y - mine.y;
    rngS[c] = make_int2(sx, sx);
    rngT[c] = make_int2(sy, sy);
}

// ---- pass 3: destructive scatter (rng.y: start -> end) ------------------
__global__ void scatter_k(const float* __restrict__ s, const float* __restrict__ t,
                          int* __restrict__ rngS, int* __restrict__ rngT,
                          float4* __restrict__ sortedS, float4* __restrict__ sortedT) {
    int i = blockIdx.x * blockDim.x + threadIdx.x;
    int cloud = i >> 14, p = i & (NPTS - 1);
    const float* base = cloud ? t : s;
    float x = base[3 * p], y = base[3 * p + 1], z = base[3 * p + 2];
    int id = (cellco(x) * GS + cellco(y)) * GS + cellco(z);
    int pos = atomicAdd((cloud ? rngT : rngS) + 2 * id + 1, 1);
    (cloud ? sortedT : sortedS)[pos] = make_float4(x, y, z, __int_as_float(p));
}

// ---- pass 4: exact NN; rings 0-1 batched one-cell-per-lane --------------
__global__ __launch_bounds__(256)
void query_k(const float4* __restrict__ sortedS, const float4* __restrict__ sortedT,
             const int2* __restrict__ rngS, const int2* __restrict__ rngT,
             const int* __restrict__ tab, float* __restrict__ out) {
    int q = blockIdx.x * QPB + (threadIdx.x >> 6);   // one wave per query
    int g = threadIdx.x & 63;
    int cloud = q >> 14, j = q & (NPTS - 1);
    float4 qp = (cloud ? sortedT : sortedS)[j];      // sorted: coherent blocks
    const float4* __restrict__ pts = cloud ? sortedS : sortedT;
    const int2* __restrict__ rng = cloud ? rngS : rngT;

    float qx = qp.x, qy = qp.y, qz = qp.z;
    int cx = cellco(qx), cy = cellco(qy), cz = cellco(qz);
    float minwall = fminf(fminf(fminf(qx - (-BBOX + cx * H), (-BBOX + (cx + 1) * H) - qx),
                                fminf(qy - (-BBOX + cy * H), (-BBOX + (cy + 1) * H) - qy)),
                          fminf(qz - (-BBOX + cz * H), (-BBOX + (cz + 1) * H) - qz));
    minwall = fmaxf(minwall, 0.0f);

    float best = 1e30f;

#define DECODE(pk, validIn, cellc, lbv)                                        \
    int cellc; float lbv;                                                      \
    {                                                                          \
        int ix = cx + ((pk) >> 10) - 15;                                       \
        int iy = cy + (((pk) >> 5) & 31) - 15;                                 \
        int iz = cz + ((pk) & 31) - 15;                                        \
        bool in = (validIn) && (unsigned)ix < GS && (unsigned)iy < GS &&       \
                  (unsigned)iz < GS;                                           \
        float clx = -BBOX + ix * H, cly = -BBOX + iy * H, clz = -BBOX + iz * H;\
        float dx = fmaxf(0.f, fmaxf(ix == 0 ? -1.f : clx - qx,                 \
                                    ix == GS - 1 ? -1.f : qx - clx - H));      \
        float dy = fmaxf(0.f, fmaxf(iy == 0 ? -1.f : cly - qy,                 \
                                    iy == GS - 1 ? -1.f : qy - cly - H));      \
        float dz = fmaxf(0.f, fmaxf(iz == 0 ? -1.f : clz - qz,                 \
                                    iz == GS - 1 ? -1.f : qz - clz - H));      \
        lbv = in ? fmaf(dx, dx, fmaf(dy, dy, dz * dz)) : 1e30f;                \
        cellc = in ? ((ix * GS + iy) * GS + iz) : 0;                           \
    }

#define PTS_SCAN(v)                                                            \
    {                                                                          \
        int k = (v).x;                                                         \
        for (; k + 2 <= (v).y; k += 2) {                                       \
            float4 p0 = pts[k], p1 = pts[k + 1];                               \
            float a0 = qx - p0.x, b0 = qy - p0.y, c0 = qz - p0.z;              \
            float a1 = qx - p1.x, b1 = qy - p1.y, c1 = qz - p1.z;              \
            best = fminf(best, fmaf(a0, a0, fmaf(b0, b0, c0 * c0)));           \
            best = fminf(best, fmaf(a1, a1, fmaf(b1, b1, c1 * c1)));           \
        }                                                                      \
        if (k < (v).y) {                                                       \
            float4 p0 = pts[k];                                                \
            float a0 = qx - p0.x, b0 = qy - p0.y, c0 = qz - p0.z;              \
            best = fminf(best, fmaf(a0, a0, fmaf(b0, b0, c0 * c0)));           \
        }                                                                      \
    }

    {   // rings 0..1 in ONE phase: tab[0..26], one cell per lane, independent
        // per-lane chains (tab -> rng -> pts). Most queries finish here.
        int pk = tab[g < 27 ? g : 0];
        DECODE(pk, g < 27, c0, lb0)
        int2 v = rng[c0];
        if (lb0 < best) PTS_SCAN(v)
    }

    for (int r = 2; r < GS; ++r) {
        float bu = best;                              // wave-uniform best
        bu = fminf(bu, __shfl_xor(bu, 1, 64));
        bu = fminf(bu, __shfl_xor(bu, 2, 64));
        bu = fminf(bu, __shfl_xor(bu, 4, 64));
        bu = fminf(bu, __shfl_xor(bu, 8, 64));
        bu = fminf(bu, __shfl_xor(bu, 16, 64));
        bu = fminf(bu, __shfl_xor(bu, 32, 64));
        float lbr = minwall + (float)(r - 1) * H;
        best = bu;
        if (lbr * lbr >= bu) break;                   // wave-uniform exit

        if (r <= RMAX) {                              // table-driven, 2-slot batch
            int w = 2 * r - 1, W = 2 * r + 1;
            int i0 = w * w * w, i1 = W * W * W;
            for (int base = i0 + g; base < i1; base += 2 * QL) {
                int iB = base + QL;
                int pkA = tab[base];                  // unconditional loads
                int pkB = tab[iB < i1 ? iB : base];
                DECODE(pkA, true, cA, lbA)
                DECODE(pkB, iB < i1, cB, lbB)
                int2 vA = rng[cA];                    // both in flight together
                int2 vB = rng[cB];
                if (lbA < best) PTS_SCAN(vA)
                if (lbB < best) PTS_SCAN(vB)
            }
        } else {                                      // r>15: NN dist > 3.5 — ~never
            unsigned W = 2 * r + 1, W2 = W * W, tot = W2 * W;
            for (unsigned idx = g; idx < tot; idx += QL) {
                unsigned q1 = idx / W2, rem = idx - q1 * W2;
                unsigned q2 = rem / W, q3 = rem - q2 * W;
                int dxo = (int)q1 - r, dyo = (int)q2 - r, dzo = (int)q3 - r;
                if (max(max(abs(dxo), abs(dyo)), abs(dzo)) != r) continue;
                int ix = cx + dxo, iy = cy + dyo, iz = cz + dzo;
                if ((unsigned)ix >= GS || (unsigned)iy >= GS || (unsigned)iz >= GS)
                    continue;
                int pk = ((ix - cx + 15) << 10) | ((iy - cy + 15) << 5) | (iz - cz + 15);
                DECODE(pk, true, cc, lbc)
                if (lbc < best) { int2 v = rng[cc]; PTS_SCAN(v) }
            }
        }
    }
#undef PTS_SCAN
#undef DECODE

    float bu = best;
    bu = fminf(bu, __shfl_xor(bu, 1, 64));
    bu = fminf(bu, __shfl_xor(bu, 2, 64));
    bu = fminf(bu, __shfl_xor(bu, 4, 64));
    bu = fminf(bu, __shfl_xor(bu, 8, 64));
    bu = fminf(bu, __shfl_xor(bu, 16, 64));
    bu = fminf(bu, __shfl_xor(bu, 32, 64));
    if (g == 0) out[cloud * NPTS + __float_as_int(qp.w)] = bu;
}

extern "C" void kernel_launch(void* const* d_in, const int* in_sizes, int n_in,
                              void* d_out, int out_size, void* d_ws, size_t ws_size,
                              hipStream_t stream) {
    const float* s = (const float*)d_in[0];
    const float* t = (const float*)d_in[1];

    int* wsI = (int*)d_ws;
    int* cntS  = wsI;                        // NC
    int* cntT  = wsI + NC;                   // NC
    int2* rngS = (int2*)(wsI + 2 * NC);      // NC int2
    int2* rngT = rngS + NC;                  // NC int2
    int* tab   = wsI + 6 * NC;               // 29792 (padded)
    int2* bsum = (int2*)(wsI + 6 * NC + 29792);          // 128 int2
    float4* sortedS = (float4*)(wsI + 6 * NC + 29792 + 256);  // NPTS
    float4* sortedT = sortedS + NPTS;                         // NPTS

    hipMemsetAsync(cntS, 0, (size_t)2 * NC * sizeof(int), stream);
    hist_k<<<(2 * NPTS + TABN + 255) / 256, 256, 0, stream>>>(s, t, cntS, cntT, tab);
    sums_k<<<NC / 256, 256, 0, stream>>>(cntS, cntT, bsum);
    scan2_k<<<NC / 256, 256, 0, stream>>>(cntS, cntT, bsum, rngS, rngT);
    scatter_k<<<(2 * NPTS) / 256, 256, 0, stream>>>(s, t, (int*)rngS, (int*)rngT,
                                                    sortedS, sortedT);
    query_k<<<(2 * NPTS) / QPB, 256, 0, stream>>>(sortedS, sortedT, rngS, rngT, tab,
                                                  (float*)d_out);
}